// Round 5
// baseline (286.786 us; speedup 1.0000x reference)
//
#include <hip/hip_runtime.h>

#define S_LEN 2048
#define NH 16
#define LOG2E 1.4426950408889634f

typedef _Float16 half8_t __attribute__((ext_vector_type(8)));
typedef _Float16 half4_t __attribute__((ext_vector_type(4)));
typedef _Float16 half2_t __attribute__((ext_vector_type(2)));
typedef float f32x4 __attribute__((ext_vector_type(4)));

__device__ __forceinline__ f32x4 mfma_qk(half8_t a, half8_t b, f32x4 c) {
  return __builtin_amdgcn_mfma_f32_16x16x32_f16(a, b, c, 0, 0, 0);
}
__device__ __forceinline__ f32x4 mfma_pv(half4_t a, half4_t b, f32x4 c) {
  return __builtin_amdgcn_mfma_f32_16x16x16f16(a, b, c, 0, 0, 0);
}
__device__ __forceinline__ void glds16(const void* g, void* l) {
  __builtin_amdgcn_global_load_lds(
      (const __attribute__((address_space(1))) unsigned int*)g,
      (__attribute__((address_space(3))) unsigned int*)l, 16, 0, 0);
}

// ---------------- fp32 -> fp16 elementwise ----------------
__global__ __launch_bounds__(256) void cvt_f16_kernel(const float* __restrict__ src,
                                                      _Float16* __restrict__ dst, int n4) {
  int i = blockIdx.x * 256 + threadIdx.x;
  if (i < n4) {
    float4 f = ((const float4*)src)[i];
    half4_t o = {(_Float16)f.x, (_Float16)f.y, (_Float16)f.z, (_Float16)f.w};
    ((half4_t*)dst)[i] = o;
  }
}

// ---------------- fp32 [K,N] -> fp16 [N,K] transpose ----------------
__global__ __launch_bounds__(256) void transpose_cvt_kernel(const float* __restrict__ W,
                                                            _Float16* __restrict__ Wt,
                                                            int K, int N) {
  __shared__ float tile[64][65];
  int k0 = blockIdx.y * 64, n0 = blockIdx.x * 64;
  int tx = threadIdx.x & 63, ty = threadIdx.x >> 6;
  for (int j = 0; j < 16; ++j) {
    int k = ty * 16 + j;
    tile[k][tx] = W[(size_t)(k0 + k) * N + n0 + tx];
  }
  __syncthreads();
  for (int j = 0; j < 16; ++j) {
    int n = ty * 16 + j;
    Wt[(size_t)(n0 + n) * K + k0 + tx] = (_Float16)tile[tx][n];
  }
}

// ---------------- fp16 GEMM: C[M,N] = A[M,K]*Bt[N,K]^T, region-aware epilogue ----
// cols [1024,2048): scaled by qscale (Q stream, folds 1/sqrt(2*DH) * log2e)
// cols >= 2048 (tok only): written to V^T layout vtg[(b*16+h)*64+dim][key]
__global__ __launch_bounds__(256) void gemm_bt_kernel(const _Float16* __restrict__ A,
                                                      const _Float16* __restrict__ Bt,
                                                      _Float16* __restrict__ C,
                                                      int M, int N, int K,
                                                      float qscale, _Float16* __restrict__ vtg) {
  __shared__ _Float16 Ald[128 * 32];
  __shared__ _Float16 Bld[128 * 32];
  const int tid = threadIdx.x;
  const int wave = tid >> 6, lane = tid & 63;
  const int quad = lane >> 4, l16 = lane & 15;
  const int m0 = blockIdx.y * 128, n0 = blockIdx.x * 128;
  const int wm = (wave >> 1) * 64, wn = (wave & 1) * 64;

  f32x4 acc[4][4] = {};
  const int flat0 = tid, flat1 = tid + 256;
  const int r0 = flat0 >> 2, c0 = flat0 & 3;
  const int r1 = flat1 >> 2, c1 = flat1 & 3;

  for (int ko = 0; ko < K; ko += 32) {
    __syncthreads();
    glds16(A + (size_t)(m0 + r0) * K + ko + c0 * 8, &Ald[flat0 * 8]);
    glds16(Bt + (size_t)(n0 + r0) * K + ko + c0 * 8, &Bld[flat0 * 8]);
    glds16(A + (size_t)(m0 + r1) * K + ko + c1 * 8, &Ald[flat1 * 8]);
    glds16(Bt + (size_t)(n0 + r1) * K + ko + c1 * 8, &Bld[flat1 * 8]);
    __syncthreads();
    half8_t af[4], bfv[4];
    #pragma unroll
    for (int t = 0; t < 4; ++t) {
      af[t]  = *(const half8_t*)&Ald[(wm + t * 16 + l16) * 32 + quad * 8];
      bfv[t] = *(const half8_t*)&Bld[(wn + t * 16 + l16) * 32 + quad * 8];
    }
    #pragma unroll
    for (int mi = 0; mi < 4; ++mi)
      #pragma unroll
      for (int ni = 0; ni < 4; ++ni)
        acc[mi][ni] = mfma_qk(af[mi], bfv[ni], acc[mi][ni]);
  }

  if (vtg != nullptr && n0 >= 2048) {
    // V region: write transposed layout, pack 4 consecutive keys per store
    #pragma unroll
    for (int mi = 0; mi < 4; ++mi)
      #pragma unroll
      for (int ni = 0; ni < 4; ++ni) {
        int n = n0 + wn + ni * 16 + l16;
        int hh = (n >> 6) & 15, dim = n & 63;
        int m = m0 + wm + mi * 16 + quad * 4;
        int bb = m >> 11, key = m & 2047;
        union { ushort4 u; _Float16 h[4]; } pk;
        #pragma unroll
        for (int r = 0; r < 4; ++r) pk.h[r] = (_Float16)acc[mi][ni][r];
        *(ushort4*)(vtg + ((size_t)((bb * 16 + hh) * 64 + dim)) * 2048 + key) = pk.u;
      }
  } else {
    float sc = (n0 >= 1024) ? qscale : 1.f;
    #pragma unroll
    for (int mi = 0; mi < 4; ++mi)
      #pragma unroll
      for (int ni = 0; ni < 4; ++ni)
        #pragma unroll
        for (int r = 0; r < 4; ++r) {
          int m = m0 + wm + mi * 16 + quad * 4 + r;
          int n = n0 + wn + ni * 16 + l16;
          C[(size_t)m * N + n] = (_Float16)(acc[mi][ni][r] * sc);
        }
  }
}

// ---------------- fused flash attention v3 ----------------
// 1024 blocks x 256 thr. Each wave owns a 16-key slice; S^T = K·Q^T so the
// P transpose for PV (O^T = V^T·P^T via 16x16x16) is a pure register pack.
// No LDS in the main loop; K/V frags stream global->VGPR (XCD-local L2).
__global__ __launch_bounds__(256, 2) void flash_kernel(const _Float16* __restrict__ tok,
                                                       const _Float16* __restrict__ poskq,
                                                       const _Float16* __restrict__ vtg,
                                                       const float* __restrict__ bias_table,
                                                       float* __restrict__ out) {
  __shared__ float biasl[384];
  __shared__ float lred[4][64];
  __shared__ __align__(16) float ored[4][64][68];

  const int tid = threadIdx.x;
  const int wave = tid >> 6, lane = tid & 63;
  const int quad = lane >> 4, l16 = lane & 15;
  const int lbid = blockIdx.x;
  const int q0 = ((lbid >> 3) & 31) * 64;               // XCD swizzle: same bh
  const int bh = (lbid & 7) + 8 * (lbid >> 8);          // stays on one XCD
  const int b = bh >> 4, h = bh & 15;

  // near-diagonal bias table (pre-scaled by log2e), exact T5 bucket thresholds.
  // NOTE: grid-stride — 384 entries > 256 threads (R4 bug: entries 256..383
  // were uninitialized with a plain `if (tid < 384)` guard).
  for (int i = tid; i < 384; i += 256) {
    int delta = i - 192;
    int n = -delta;
    int ret = (n < 0) ? 16 : 0;
    int na = (n < 0) ? -n : n;
    int bkt;
    if (na < 8) bkt = na;
    else {
      int s2 = (na >= 12) + (na >= 16) + (na >= 23) + (na >= 32) +
               (na >= 46) + (na >= 64) + (na >= 91) + (na >= 128);
      bkt = 8 + s2; if (bkt > 15) bkt = 15;
    }
    bkt += ret;
    biasl[i] = bias_table[(size_t)(2048 + bkt) * NH + h] * LOG2E;
  }
  const float b_lo = bias_table[(2048 + 15) * NH + h] * LOG2E;  // delta <= -129
  const float b_hi = bias_table[(2048 + 31) * NH + h] * LOG2E;  // delta >= +129
  __syncthreads();

  // Q B-fragments [kf][qt] (Q pre-scaled by qs*log2e in gemm epilogue)
  half8_t qf[4][4];
  {
    const _Float16* tq = tok + (size_t)(b * S_LEN + q0 + l16) * 3072 + 1024 + h * 64 + quad * 8;
    const _Float16* pq = poskq + (size_t)(q0 + l16) * 2048 + 1024 + h * 64 + quad * 8;
    #pragma unroll
    for (int qt = 0; qt < 4; ++qt)
      #pragma unroll
      for (int kf = 0; kf < 2; ++kf) {
        qf[kf][qt]     = *(const half8_t*)(tq + (size_t)qt * 16 * 3072 + kf * 32);
        qf[kf + 2][qt] = *(const half8_t*)(pq + (size_t)qt * 16 * 2048 + kf * 32);
      }
  }

  // per-lane K/V stream pointers (wave's 16-key slice)
  const _Float16* kpt = tok + (size_t)(b * S_LEN + wave * 16 + l16) * 3072 + h * 64 + quad * 8;
  const _Float16* kpp = poskq + (size_t)(wave * 16 + l16) * 2048 + h * 64 + quad * 8;
  const _Float16* vp  = vtg + (size_t)(bh * 64 + l16) * 2048 + wave * 16 + quad * 4;

  f32x4 oa[4][4] = {};                 // O^T partial [d][qt]
  float lpart[4] = {0.f, 0.f, 0.f, 0.f};

  half8_t ka[4], kb[4];
  half4_t va[4], vb[4];

  auto load_tile = [&](int k0i, half8_t (&kf_)[4], half4_t (&vf_)[4]) {
    const _Float16* a = kpt + (size_t)k0i * 3072;
    const _Float16* p = kpp + (size_t)k0i * 2048;
    kf_[0] = *(const half8_t*)a;
    kf_[1] = *(const half8_t*)(a + 32);
    kf_[2] = *(const half8_t*)p;
    kf_[3] = *(const half8_t*)(p + 32);
    const _Float16* v = vp + k0i;
    #pragma unroll
    for (int d = 0; d < 4; ++d) vf_[d] = *(const half4_t*)(v + (size_t)(d * 16) * 2048);
  };

  auto compute = [&](int k0i, half8_t (&kf_)[4], half4_t (&vf_)[4]) {
    f32x4 s[4];
    int dk = k0i - q0;
    if (dk < -128 || dk > 128) {           // far field: bias constant per side
      float c = (dk < 0) ? b_lo : b_hi;
      #pragma unroll
      for (int qt = 0; qt < 4; ++qt) s[qt] = {c, c, c, c};
    } else {                               // 5 near tiles: table
      #pragma unroll
      for (int qt = 0; qt < 4; ++qt) {
        int dbase = dk + wave * 16 + quad * 4 - qt * 16 - l16 + 192;
        #pragma unroll
        for (int r = 0; r < 4; ++r) s[qt][r] = biasl[dbase + r];
      }
    }
    #pragma unroll
    for (int qt = 0; qt < 4; ++qt)
      #pragma unroll
      for (int kf = 0; kf < 4; ++kf)
        s[qt] = mfma_qk(kf_[kf], qf[kf][qt], s[qt]);

    half4_t pf[4];
    #pragma unroll
    for (int qt = 0; qt < 4; ++qt) {
      float p0 = exp2f(s[qt][0]), p1 = exp2f(s[qt][1]);
      float p2 = exp2f(s[qt][2]), p3 = exp2f(s[qt][3]);
      lpart[qt] += (p0 + p1) + (p2 + p3);
      union { half2_t h2[2]; half4_t h4; } u;
      u.h2[0] = __builtin_bit_cast(half2_t, __builtin_amdgcn_cvt_pkrtz(p0, p1));
      u.h2[1] = __builtin_bit_cast(half2_t, __builtin_amdgcn_cvt_pkrtz(p2, p3));
      pf[qt] = u.h4;
    }
    #pragma unroll
    for (int d = 0; d < 4; ++d)
      #pragma unroll
      for (int qt = 0; qt < 4; ++qt)
        oa[d][qt] = mfma_pv(vf_[d], pf[qt], oa[d][qt]);
  };

  load_tile(0, ka, va);
  #pragma unroll 1
  for (int i = 0; i < 16; ++i) {
    int t0 = i * 128;
    load_tile(t0 + 64, kb, vb);            // prefetch odd tile
    compute(t0, ka, va);
    if (i != 15) load_tile(t0 + 128, ka, va);  // prefetch next even tile
    compute(t0 + 64, kb, vb);
  }

  // l: sum quads in-wave, then cross-wave via LDS
  #pragma unroll
  for (int qt = 0; qt < 4; ++qt) {
    lpart[qt] += __shfl_xor(lpart[qt], 16, 64);
    lpart[qt] += __shfl_xor(lpart[qt], 32, 64);
  }
  if (quad == 0) {
    #pragma unroll
    for (int qt = 0; qt < 4; ++qt) lred[wave][qt * 16 + l16] = lpart[qt];
  }
  #pragma unroll
  for (int d = 0; d < 4; ++d)
    #pragma unroll
    for (int qt = 0; qt < 4; ++qt)
      *(f32x4*)&ored[wave][qt * 16 + l16][d * 16 + quad * 4] = oa[d][qt];
  __syncthreads();

  // cross-wave O reduction + softmax normalize + store
  #pragma unroll
  for (int c = 0; c < 4; ++c) {
    int chunk = tid + 256 * c;             // 0..1023
    int q = chunk >> 4, dc = chunk & 15;
    f32x4 v0 = *(const f32x4*)&ored[0][q][dc * 4];
    f32x4 v1 = *(const f32x4*)&ored[1][q][dc * 4];
    f32x4 v2 = *(const f32x4*)&ored[2][q][dc * 4];
    f32x4 v3 = *(const f32x4*)&ored[3][q][dc * 4];
    f32x4 sum = (v0 + v1) + (v2 + v3);
    float l = (lred[0][q] + lred[1][q]) + (lred[2][q] + lred[3][q]);
    float inv = 1.f / l;
    sum[0] *= inv; sum[1] *= inv; sum[2] *= inv; sum[3] *= inv;
    *(f32x4*)(out + (size_t)(b * S_LEN + q0 + q) * 1024 + h * 64 + dc * 4) = sum;
  }
}

extern "C" void kernel_launch(void* const* d_in, const int* in_sizes, int n_in,
                              void* d_out, int out_size, void* d_ws, size_t ws_size,
                              hipStream_t stream) {
  (void)in_sizes; (void)n_in; (void)out_size; (void)ws_size;
  const float* x          = (const float*)d_in[0];
  const float* pos_embed  = (const float*)d_in[1];
  const float* W_pos_kq   = (const float*)d_in[2];
  const float* W_tok_kqv  = (const float*)d_in[3];
  const float* bias_table = (const float*)d_in[4];
  float* out = (float*)d_out;

  _Float16* ws = (_Float16*)d_ws;
  // phase-1: pos stream in region [0, 4M) which is later overlaid by vtg
  _Float16* pos_f  = ws;                   // 2,097,152
  _Float16* wt_pos = ws + 2097152;         // 2,097,152
  _Float16* vtg    = ws;                   // 4,194,304 (valid after pos gemm done)
  _Float16* x_f    = ws + 4194304;         // 4,194,304
  _Float16* wt_tok = ws + 8388608;         // 3,145,728
  _Float16* tok_f  = ws + 11534336;        // 12,582,912
  _Float16* poskq  = ws + 24117248;        // 4,194,304   (total 56.6 MB)

  const float QSCALE = 0.08838834764831845f * LOG2E;  // 1/sqrt(2*64) * log2e

  // pos stream first so its buffers can be overlaid by vtg
  cvt_f16_kernel<<<2048, 256, 0, stream>>>(pos_embed, pos_f, 2048 * 1024 / 4);
  transpose_cvt_kernel<<<dim3(32, 16), 256, 0, stream>>>(W_pos_kq, wt_pos, 1024, 2048);
  gemm_bt_kernel<<<dim3(16, 16), 256, 0, stream>>>(pos_f, wt_pos, poskq, 2048, 2048, 1024,
                                                   QSCALE, nullptr);
  cvt_f16_kernel<<<4096, 256, 0, stream>>>(x, x_f, 4096 * 1024 / 4);
  transpose_cvt_kernel<<<dim3(48, 16), 256, 0, stream>>>(W_tok_kqv, wt_tok, 1024, 3072);
  gemm_bt_kernel<<<dim3(24, 32), 256, 0, stream>>>(x_f, wt_tok, tok_f, 4096, 3072, 1024,
                                                   QSCALE, vtg);
  flash_kernel<<<1024, 256, 0, stream>>>(tok_f, poskq, vtg, bias_table, out);
}

// Round 6
// 238.989 us; speedup vs baseline: 1.2000x; 1.2000x over previous
//
#include <hip/hip_runtime.h>

#define S_LEN 2048
#define NH 16
#define LOG2E 1.4426950408889634f

typedef _Float16 half8_t __attribute__((ext_vector_type(8)));
typedef _Float16 half4_t __attribute__((ext_vector_type(4)));
typedef _Float16 half2_t __attribute__((ext_vector_type(2)));
typedef float f32x4 __attribute__((ext_vector_type(4)));

__device__ __forceinline__ f32x4 mfma_qk(half8_t a, half8_t b, f32x4 c) {
  return __builtin_amdgcn_mfma_f32_16x16x32_f16(a, b, c, 0, 0, 0);
}
__device__ __forceinline__ f32x4 mfma_pv(half4_t a, half4_t b, f32x4 c) {
  return __builtin_amdgcn_mfma_f32_16x16x16f16(a, b, c, 0, 0, 0);
}
__device__ __forceinline__ void glds16(const void* g, void* l) {
  __builtin_amdgcn_global_load_lds(
      (const __attribute__((address_space(1))) unsigned int*)g,
      (__attribute__((address_space(3))) unsigned int*)l, 16, 0, 0);
}

// ---------------- fp32 -> fp16 elementwise ----------------
__global__ __launch_bounds__(256) void cvt_f16_kernel(const float* __restrict__ src,
                                                      _Float16* __restrict__ dst, int n4) {
  int i = blockIdx.x * 256 + threadIdx.x;
  if (i < n4) {
    float4 f = ((const float4*)src)[i];
    half4_t o = {(_Float16)f.x, (_Float16)f.y, (_Float16)f.z, (_Float16)f.w};
    ((half4_t*)dst)[i] = o;
  }
}

// ---------------- fp32 [K,N] -> fp16 [N,K] transpose ----------------
__global__ __launch_bounds__(256) void transpose_cvt_kernel(const float* __restrict__ W,
                                                            _Float16* __restrict__ Wt,
                                                            int K, int N) {
  __shared__ float tile[64][65];
  int k0 = blockIdx.y * 64, n0 = blockIdx.x * 64;
  int tx = threadIdx.x & 63, ty = threadIdx.x >> 6;
  for (int j = 0; j < 16; ++j) {
    int k = ty * 16 + j;
    tile[k][tx] = W[(size_t)(k0 + k) * N + n0 + tx];
  }
  __syncthreads();
  for (int j = 0; j < 16; ++j) {
    int n = ty * 16 + j;
    Wt[(size_t)(n0 + n) * K + k0 + tx] = (_Float16)tile[tx][n];
  }
}

// ---------------- fp16 GEMM with fragment-layout epilogues ----------------
// n in [0,1024):    K stream -> KG/KGP wave-fragment layout (LDS transpose)
// n in [1024,2048): Q stream -> row-major qr, scaled by qscale
// n >= 2048:        V stream -> VG fragment layout (register repack)
// tok mode: vg != nullptr (M=4096, N=3072, kg=KG[bh]); pos: vg==nullptr (kg=KGP[h])
__global__ __launch_bounds__(256) void gemm_bt_kernel(const _Float16* __restrict__ A,
                                                      const _Float16* __restrict__ Bt,
                                                      int M, int N, int K, float qscale,
                                                      _Float16* __restrict__ kg,
                                                      _Float16* __restrict__ qr,
                                                      _Float16* __restrict__ vg) {
  __shared__ _Float16 Ald[128 * 32];
  __shared__ _Float16 Bld[128 * 32];
  __shared__ _Float16 EpiLds[4][4096];   // per-wave 8KB transpose scratch
  const int tid = threadIdx.x;
  const int wave = tid >> 6, lane = tid & 63;
  const int quad = lane >> 4, l16 = lane & 15;
  const int m0 = blockIdx.y * 128, n0 = blockIdx.x * 128;
  const int wm = (wave >> 1) * 64, wn = (wave & 1) * 64;

  f32x4 acc[4][4] = {};
  const int flat0 = tid, flat1 = tid + 256;
  const int r0 = flat0 >> 2, c0 = flat0 & 3;
  const int r1 = flat1 >> 2, c1 = flat1 & 3;

  for (int ko = 0; ko < K; ko += 32) {
    __syncthreads();
    glds16(A + (size_t)(m0 + r0) * K + ko + c0 * 8, &Ald[flat0 * 8]);
    glds16(Bt + (size_t)(n0 + r0) * K + ko + c0 * 8, &Bld[flat0 * 8]);
    glds16(A + (size_t)(m0 + r1) * K + ko + c1 * 8, &Ald[flat1 * 8]);
    glds16(Bt + (size_t)(n0 + r1) * K + ko + c1 * 8, &Bld[flat1 * 8]);
    __syncthreads();
    half8_t af[4], bfv[4];
    #pragma unroll
    for (int t = 0; t < 4; ++t) {
      af[t]  = *(const half8_t*)&Ald[(wm + t * 16 + l16) * 32 + quad * 8];
      bfv[t] = *(const half8_t*)&Bld[(wn + t * 16 + l16) * 32 + quad * 8];
    }
    #pragma unroll
    for (int mi = 0; mi < 4; ++mi)
      #pragma unroll
      for (int ni = 0; ni < 4; ++ni)
        acc[mi][ni] = mfma_qk(af[mi], bfv[ni], acc[mi][ni]);
  }

  const int n_base = n0 + wn, m_base = m0 + wm;   // both 64-aligned
  const int bb = m_base >> 11;
  const int tile = (m_base & 2047) >> 6;

  if (n_base >= 2048) {
    // V region (tok only): VG[bh][tile][wavek=mi][d=ni][quadv=quad][l16v=l16][4 keys]
    int hh = (n_base >> 6) & 15;
    _Float16* dstb = vg + (size_t)((bb * 16 + hh) * 32 + tile) * 4096;
    #pragma unroll
    for (int mi = 0; mi < 4; ++mi)
      #pragma unroll
      for (int ni = 0; ni < 4; ++ni) {
        union { ushort4 u; _Float16 h[4]; } pk;
        #pragma unroll
        for (int r = 0; r < 4; ++r) pk.h[r] = (_Float16)acc[mi][ni][r];
        *(ushort4*)(dstb + ((mi * 4 + ni) * 4 + quad) * 64 + l16 * 4) = pk.u;
      }
  } else if (n_base >= 1024) {
    // Q region: row-major, scaled
    #pragma unroll
    for (int mi = 0; mi < 4; ++mi)
      #pragma unroll
      for (int ni = 0; ni < 4; ++ni)
        #pragma unroll
        for (int r = 0; r < 4; ++r) {
          int m = m_base + mi * 16 + quad * 4 + r;
          int col = n_base - 1024 + ni * 16 + l16;
          qr[(size_t)m * 1024 + col] = (_Float16)(acc[mi][ni][r] * qscale);
        }
  } else {
    // K region: in-lane dim-transpose via xor-swizzled per-wave LDS
    int hh = n_base >> 6;
    _Float16* Tr = &EpiLds[wave][0];
    #pragma unroll
    for (int mi = 0; mi < 4; ++mi)
      #pragma unroll
      for (int ni = 0; ni < 4; ++ni)
        #pragma unroll
        for (int r = 0; r < 4; ++r) {
          int key = mi * 16 + quad * 4 + r;
          int dim = ni * 16 + l16;
          int col = (((dim >> 3) ^ (key & 7)) << 3) | (dim & 7);
          Tr[key * 64 + col] = (_Float16)acc[mi][ni][r];
        }
    int bhk = vg ? (bb * 16 + hh) : hh;     // pos K is batch-independent
    _Float16* dstb = kg + (size_t)(bhk * 32 + tile) * 4096;
    #pragma unroll
    for (int j = 0; j < 8; ++j) {
      int wk = j >> 1, kfl = j & 1;
      half8_t v = *(const half8_t*)&Tr[(wk * 16 + l16) * 64 +
                                       ((((kfl * 4 + quad) ^ (l16 & 7))) << 3)];
      *(half8_t*)(dstb + wk * 1024 + kfl * 512 + quad * 128 + l16 * 8) = v;
    }
  }
}

// ---------------- fused flash attention v4 ----------------
// Barrier-free main loop, all K/V loads fragment-major (base + lane*16B).
__global__ __launch_bounds__(256, 2) void flash_kernel(const _Float16* __restrict__ QRt,
                                                       const _Float16* __restrict__ QRp,
                                                       const _Float16* __restrict__ KG,
                                                       const _Float16* __restrict__ KGP,
                                                       const _Float16* __restrict__ VG,
                                                       const float* __restrict__ bias_table,
                                                       float* __restrict__ out) {
  __shared__ float biasl[384];
  __shared__ float lred[4][64];
  __shared__ __align__(16) float ored2[2][64][68];

  const int tid = threadIdx.x;
  const int wave = tid >> 6, lane = tid & 63;
  const int quad = lane >> 4, l16 = lane & 15;
  const int lbid = blockIdx.x;
  const int q0 = ((lbid >> 3) & 31) * 64;        // XCD swizzle: same bh
  const int bh = (lbid & 7) + 8 * (lbid >> 8);   // stays on one XCD
  const int b = bh >> 4, h = bh & 15;

  for (int i = tid; i < 384; i += 256) {
    int delta = i - 192;
    int n = -delta;
    int ret = (n < 0) ? 16 : 0;
    int na = (n < 0) ? -n : n;
    int bkt;
    if (na < 8) bkt = na;
    else {
      int s2 = (na >= 12) + (na >= 16) + (na >= 23) + (na >= 32) +
               (na >= 46) + (na >= 64) + (na >= 91) + (na >= 128);
      bkt = 8 + s2; if (bkt > 15) bkt = 15;
    }
    bkt += ret;
    biasl[i] = bias_table[(size_t)(2048 + bkt) * NH + h] * LOG2E;
  }
  const float b_lo = bias_table[(2048 + 15) * NH + h] * LOG2E;
  const float b_hi = bias_table[(2048 + 31) * NH + h] * LOG2E;
  __syncthreads();

  // Q fragments (rows; strided once per block), pre-scaled in gemm epilogue
  half8_t qf[4][4];
  {
    const _Float16* tq = QRt + (size_t)(b * S_LEN + q0 + l16) * 1024 + h * 64 + quad * 8;
    const _Float16* pq = QRp + (size_t)(q0 + l16) * 1024 + h * 64 + quad * 8;
    #pragma unroll
    for (int qt = 0; qt < 4; ++qt)
      #pragma unroll
      for (int kf = 0; kf < 2; ++kf) {
        qf[kf][qt]     = *(const half8_t*)(tq + (size_t)qt * 16 * 1024 + kf * 32);
        qf[kf + 2][qt] = *(const half8_t*)(pq + (size_t)qt * 16 * 1024 + kf * 32);
      }
  }

  // fragment-major stream pointers (fully coalesced: base + lane*16B / *8B)
  const _Float16* kp_t = KG  + (size_t)bh * 131072 + wave * 1024 + lane * 8;
  const _Float16* kp_p = KGP + (size_t)h  * 131072 + wave * 1024 + lane * 8;
  const _Float16* vp   = VG  + (size_t)bh * 131072 + wave * 1024 + lane * 4;

  f32x4 oa[4][4] = {};
  float lpart[4] = {0.f, 0.f, 0.f, 0.f};

  half8_t ka[4], kb[4];
  half4_t va[4], vb[4];

  auto load_tile = [&](int t, half8_t (&kf_)[4], half4_t (&vf_)[4]) {
    const _Float16* kt = kp_t + t * 4096;
    const _Float16* kp = kp_p + t * 4096;
    kf_[0] = *(const half8_t*)kt;
    kf_[1] = *(const half8_t*)(kt + 512);
    kf_[2] = *(const half8_t*)kp;
    kf_[3] = *(const half8_t*)(kp + 512);
    const _Float16* v = vp + t * 4096;
    #pragma unroll
    for (int d = 0; d < 4; ++d) vf_[d] = *(const half4_t*)(v + d * 256);
  };

  auto compute = [&](int t, half8_t (&kf_)[4], half4_t (&vf_)[4]) {
    f32x4 s[4];
    int dk = t * 64 - q0;
    if (dk < -128 || dk > 128) {
      float c = (dk < 0) ? b_lo : b_hi;
      #pragma unroll
      for (int qt = 0; qt < 4; ++qt) s[qt] = {c, c, c, c};
    } else {
      #pragma unroll
      for (int qt = 0; qt < 4; ++qt) {
        int dbase = dk + wave * 16 + quad * 4 - qt * 16 - l16 + 192;
        #pragma unroll
        for (int r = 0; r < 4; ++r) s[qt][r] = biasl[dbase + r];
      }
    }
    #pragma unroll
    for (int qt = 0; qt < 4; ++qt)
      #pragma unroll
      for (int kf = 0; kf < 4; ++kf)
        s[qt] = mfma_qk(kf_[kf], qf[kf][qt], s[qt]);

    half4_t pf[4];
    #pragma unroll
    for (int qt = 0; qt < 4; ++qt) {
      float p0 = exp2f(s[qt][0]), p1 = exp2f(s[qt][1]);
      float p2 = exp2f(s[qt][2]), p3 = exp2f(s[qt][3]);
      lpart[qt] += (p0 + p1) + (p2 + p3);
      union { half2_t h2[2]; half4_t h4; } u;
      u.h2[0] = __builtin_bit_cast(half2_t, __builtin_amdgcn_cvt_pkrtz(p0, p1));
      u.h2[1] = __builtin_bit_cast(half2_t, __builtin_amdgcn_cvt_pkrtz(p2, p3));
      pf[qt] = u.h4;
    }
    #pragma unroll
    for (int d = 0; d < 4; ++d)
      #pragma unroll
      for (int qt = 0; qt < 4; ++qt)
        oa[d][qt] = mfma_pv(vf_[d], pf[qt], oa[d][qt]);
  };

  load_tile(0, ka, va);
  #pragma unroll 1
  for (int i = 0; i < 16; ++i) {
    int t0 = i * 2;
    load_tile(t0 + 1, kb, vb);
    compute(t0, ka, va);
    if (i != 15) load_tile(t0 + 2, ka, va);
    compute(t0 + 1, kb, vb);
  }

  // l: quad-reduce in-wave, publish
  #pragma unroll
  for (int qt = 0; qt < 4; ++qt) {
    lpart[qt] += __shfl_xor(lpart[qt], 16, 64);
    lpart[qt] += __shfl_xor(lpart[qt], 32, 64);
  }
  if (quad == 0) {
    #pragma unroll
    for (int qt = 0; qt < 4; ++qt) lred[wave][qt * 16 + l16] = lpart[qt];
  }
  // two-phase O reduction (halves LDS vs 4-buffer version)
  if (wave >= 2) {
    #pragma unroll
    for (int d = 0; d < 4; ++d)
      #pragma unroll
      for (int qt = 0; qt < 4; ++qt)
        *(f32x4*)&ored2[wave - 2][qt * 16 + l16][d * 16 + quad * 4] = oa[d][qt];
  }
  __syncthreads();
  if (wave < 2) {
    #pragma unroll
    for (int d = 0; d < 4; ++d)
      #pragma unroll
      for (int qt = 0; qt < 4; ++qt) {
        f32x4 p = *(const f32x4*)&ored2[wave][qt * 16 + l16][d * 16 + quad * 4];
        *(f32x4*)&ored2[wave][qt * 16 + l16][d * 16 + quad * 4] = oa[d][qt] + p;
      }
  }
  __syncthreads();

  #pragma unroll
  for (int c = 0; c < 4; ++c) {
    int chunk = tid + 256 * c;             // 0..1023
    int q = chunk >> 4, dc = chunk & 15;
    f32x4 v0 = *(const f32x4*)&ored2[0][q][dc * 4];
    f32x4 v1 = *(const f32x4*)&ored2[1][q][dc * 4];
    f32x4 sum = v0 + v1;
    float l = (lred[0][q] + lred[1][q]) + (lred[2][q] + lred[3][q]);
    float inv = 1.f / l;
    sum[0] *= inv; sum[1] *= inv; sum[2] *= inv; sum[3] *= inv;
    *(f32x4*)(out + (size_t)(b * S_LEN + q0 + q) * 1024 + h * 64 + dc * 4) = sum;
  }
}

extern "C" void kernel_launch(void* const* d_in, const int* in_sizes, int n_in,
                              void* d_out, int out_size, void* d_ws, size_t ws_size,
                              hipStream_t stream) {
  (void)in_sizes; (void)n_in; (void)out_size; (void)ws_size;
  const float* x          = (const float*)d_in[0];
  const float* pos_embed  = (const float*)d_in[1];
  const float* W_pos_kq   = (const float*)d_in[2];
  const float* W_tok_kqv  = (const float*)d_in[3];
  const float* bias_table = (const float*)d_in[4];
  float* out = (float*)d_out;

  _Float16* ws = (_Float16*)d_ws;
  // phase-1 (pos): pos_f@0 (2M), wt_pos@2M (2M); phase-2 (tok): x_f@0 (4M) overlays
  _Float16* pos_f  = ws;                     // 2,097,152
  _Float16* wt_pos = ws + 2097152;           // 2,097,152
  _Float16* x_f    = ws;                     // 4,194,304 (after pos gemm)
  _Float16* wt_tok = ws + 4194304;           // 3,145,728
  _Float16* KG     = ws + 7340032;           // 4,194,304  tok-K frags [bh]
  _Float16* KGP    = ws + 11534336;          // 2,097,152  pos-K frags [h]
  _Float16* VG     = ws + 13631488;          // 4,194,304  V frags [bh]
  _Float16* QRt    = ws + 17825792;          // 4,194,304  tok-Q rows
  _Float16* QRp    = ws + 22020096;          // 2,097,152  pos-Q rows
  // total 24,117,248 halfs = 48.2 MB

  const float QSCALE = 0.08838834764831845f * LOG2E;  // 1/sqrt(2*64) * log2e

  cvt_f16_kernel<<<2048, 256, 0, stream>>>(pos_embed, pos_f, 2048 * 1024 / 4);
  transpose_cvt_kernel<<<dim3(32, 16), 256, 0, stream>>>(W_pos_kq, wt_pos, 1024, 2048);
  gemm_bt_kernel<<<dim3(16, 16), 256, 0, stream>>>(pos_f, wt_pos, 2048, 2048, 1024,
                                                   QSCALE, KGP, QRp, nullptr);
  cvt_f16_kernel<<<4096, 256, 0, stream>>>(x, x_f, 4096 * 1024 / 4);
  transpose_cvt_kernel<<<dim3(48, 16), 256, 0, stream>>>(W_tok_kqv, wt_tok, 1024, 3072);
  gemm_bt_kernel<<<dim3(24, 32), 256, 0, stream>>>(x_f, wt_tok, 4096, 3072, 1024,
                                                   QSCALE, KG, QRt, VG);
  flash_kernel<<<1024, 256, 0, stream>>>(QRt, QRp, KG, KGP, VG, bias_table, out);
}

// Round 7
// 205.211 us; speedup vs baseline: 1.3975x; 1.1646x over previous
//
#include <hip/hip_runtime.h>

#define S_LEN 2048
#define NH 16
#define LOG2E 1.4426950408889634f

typedef _Float16 half8_t __attribute__((ext_vector_type(8)));
typedef _Float16 half4_t __attribute__((ext_vector_type(4)));
typedef _Float16 half2_t __attribute__((ext_vector_type(2)));
typedef float f32x4 __attribute__((ext_vector_type(4)));

__device__ __forceinline__ f32x4 mfma_qk(half8_t a, half8_t b, f32x4 c) {
  return __builtin_amdgcn_mfma_f32_16x16x32_f16(a, b, c, 0, 0, 0);
}
__device__ __forceinline__ f32x4 mfma_pv(half4_t a, half4_t b, f32x4 c) {
  return __builtin_amdgcn_mfma_f32_16x16x16f16(a, b, c, 0, 0, 0);
}
__device__ __forceinline__ void glds16(const void* g, void* l) {
  __builtin_amdgcn_global_load_lds(
      (const __attribute__((address_space(1))) unsigned int*)g,
      (__attribute__((address_space(3))) unsigned int*)l, 16, 0, 0);
}
__device__ __forceinline__ float fexp2(float x) {
#if __has_builtin(__builtin_amdgcn_exp2f)
  return __builtin_amdgcn_exp2f(x);   // raw v_exp_f32, 1 instr
#else
  return exp2f(x);
#endif
}

// ---------------- fused prep: fp32->fp16 cvts + both weight transposes ----------
__global__ __launch_bounds__(256) void prep_kernel(const float* __restrict__ x,
                                                   const float* __restrict__ pos_embed,
                                                   const float* __restrict__ W_pos,
                                                   const float* __restrict__ W_tok,
                                                   _Float16* __restrict__ x_f,
                                                   _Float16* __restrict__ pos_f,
                                                   _Float16* __restrict__ wt_pos,
                                                   _Float16* __restrict__ wt_tok) {
  __shared__ float tile[64][65];
  const int bid = blockIdx.x, tid = threadIdx.x;
  if (bid < 6144) {
    // elementwise cvt: 1,572,864 float4 total (pos_embed first 524288, then x)
    int id = bid * 256 + tid;
    const float* src; _Float16* dst;
    if (id < 524288) { src = pos_embed; dst = pos_f; }
    else { id -= 524288; src = x; dst = x_f; }
    float4 f = ((const float4*)src)[id];
    half4_t o = {(_Float16)f.x, (_Float16)f.y, (_Float16)f.z, (_Float16)f.w};
    ((half4_t*)dst)[id] = o;
    return;
  }
  // weight transpose fp32 [K,N] -> fp16 [N,K], K=1024
  const float* W; _Float16* Wt; int N, nx, ky;
  if (bid < 6656) { W = W_pos; Wt = wt_pos; N = 2048; int t = bid - 6144; nx = t & 31; ky = t >> 5; }
  else            { W = W_tok; Wt = wt_tok; N = 3072; int t = bid - 6656; nx = t % 48; ky = t / 48; }
  int k0 = ky * 64, n0 = nx * 64;
  int tx = tid & 63, ty = tid >> 6;
  for (int j = 0; j < 16; ++j) {
    int k = ty * 16 + j;
    tile[k][tx] = W[(size_t)(k0 + k) * N + n0 + tx];
  }
  __syncthreads();
  for (int j = 0; j < 16; ++j) {
    int n = ty * 16 + j;
    Wt[(size_t)(n0 + n) * 1024 + k0 + tx] = (_Float16)tile[tx][n];
  }
}

// ---------------- merged fp16 GEMM (pos + tok), fragment-layout epilogues ------
// blocks [0,256):   pos gemm  2048x2048, A=pos_f, Bt=wt_pos, kg=KGP, qr=QRp
// blocks [256,1024): tok gemm 4096x3072, A=x_f,  Bt=wt_tok, kg=KG,  qr=QRt, vg=VG
// n in [0,1024): K stream (2-round LDS transpose, scratch overlaid on staging LDS)
// n in [1024,2048): Q stream row-major, scaled; n >= 2048: V fragment layout
__global__ __launch_bounds__(256) void gemm_all_kernel(const _Float16* __restrict__ pos_f,
                                                       const _Float16* __restrict__ wt_pos,
                                                       const _Float16* __restrict__ x_f,
                                                       const _Float16* __restrict__ wt_tok,
                                                       _Float16* __restrict__ KGP,
                                                       _Float16* __restrict__ QRp,
                                                       _Float16* __restrict__ KG,
                                                       _Float16* __restrict__ QRt,
                                                       _Float16* __restrict__ VG,
                                                       float qscale) {
  __shared__ _Float16 SMem[8192];        // 16 KB: staging (Ald|Bld), reused by epilogue
  _Float16* Ald = SMem;
  _Float16* Bld = SMem + 4096;

  const int bid = blockIdx.x, tid = threadIdx.x;
  const _Float16 *A, *Bt; _Float16 *kg, *qr, *vg;
  int m0, n0;
  if (bid < 256) {
    A = pos_f; Bt = wt_pos; kg = KGP; qr = QRp; vg = nullptr;
    m0 = (bid >> 4) * 128; n0 = (bid & 15) * 128;
  } else {
    int t = bid - 256;
    A = x_f; Bt = wt_tok; kg = KG; qr = QRt; vg = VG;
    m0 = (t / 24) * 128; n0 = (t % 24) * 128;
  }
  const int K = 1024;

  const int wave = tid >> 6, lane = tid & 63;
  const int quad = lane >> 4, l16 = lane & 15;
  const int wm = (wave >> 1) * 64, wn = (wave & 1) * 64;

  f32x4 acc[4][4] = {};
  const int flat0 = tid, flat1 = tid + 256;
  const int r0 = flat0 >> 2, c0 = flat0 & 3;
  const int r1 = flat1 >> 2, c1 = flat1 & 3;

  for (int ko = 0; ko < K; ko += 32) {
    __syncthreads();
    glds16(A + (size_t)(m0 + r0) * K + ko + c0 * 8, &Ald[flat0 * 8]);
    glds16(Bt + (size_t)(n0 + r0) * K + ko + c0 * 8, &Bld[flat0 * 8]);
    glds16(A + (size_t)(m0 + r1) * K + ko + c1 * 8, &Ald[flat1 * 8]);
    glds16(Bt + (size_t)(n0 + r1) * K + ko + c1 * 8, &Bld[flat1 * 8]);
    __syncthreads();
    half8_t af[4], bfv[4];
    #pragma unroll
    for (int t = 0; t < 4; ++t) {
      af[t]  = *(const half8_t*)&Ald[(wm + t * 16 + l16) * 32 + quad * 8];
      bfv[t] = *(const half8_t*)&Bld[(wn + t * 16 + l16) * 32 + quad * 8];
    }
    #pragma unroll
    for (int mi = 0; mi < 4; ++mi)
      #pragma unroll
      for (int ni = 0; ni < 4; ++ni)
        acc[mi][ni] = mfma_qk(af[mi], bfv[ni], acc[mi][ni]);
  }
  __syncthreads();   // protect SMem before epilogue scratch reuse

  const int n_base = n0 + wn, m_base = m0 + wm;   // both 64-aligned
  const int bb = m_base >> 11;
  const int tile16 = (m_base & 2047) >> 6;

  if (n_base >= 2048) {
    // V region (tok only): VG[bh][tile][mi][ni=d][quad][l16][4 keys]
    int hh = (n_base >> 6) & 15;
    _Float16* dstb = vg + (size_t)((bb * 16 + hh) * 32 + tile16) * 4096;
    #pragma unroll
    for (int mi = 0; mi < 4; ++mi)
      #pragma unroll
      for (int ni = 0; ni < 4; ++ni) {
        union { ushort4 u; _Float16 h[4]; } pk;
        #pragma unroll
        for (int r = 0; r < 4; ++r) pk.h[r] = (_Float16)acc[mi][ni][r];
        *(ushort4*)(dstb + ((mi * 4 + ni) * 4 + quad) * 64 + l16 * 4) = pk.u;
      }
  } else if (n_base >= 1024) {
    // Q region: row-major, scaled
    #pragma unroll
    for (int mi = 0; mi < 4; ++mi)
      #pragma unroll
      for (int ni = 0; ni < 4; ++ni)
        #pragma unroll
        for (int r = 0; r < 4; ++r) {
          int m = m_base + mi * 16 + quad * 4 + r;
          int col = n_base - 1024 + ni * 16 + l16;
          qr[(size_t)m * 1024 + col] = (_Float16)(acc[mi][ni][r] * qscale);
        }
  } else {
    // K region: in-lane dim-transpose, 2 rounds of 32 keys through 4 KB/wave scratch
    int hh = n_base >> 6;
    int bhk = vg ? (bb * 16 + hh) : hh;
    _Float16* dstb = kg + (size_t)(bhk * 32 + tile16) * 4096;
    _Float16* Tr = SMem + wave * 2048;       // per-wave private 4 KB
    #pragma unroll
    for (int p = 0; p < 2; ++p) {
      #pragma unroll
      for (int mi2 = 0; mi2 < 2; ++mi2) {
        int mi = p * 2 + mi2;
        #pragma unroll
        for (int ni = 0; ni < 4; ++ni)
          #pragma unroll
          for (int r = 0; r < 4; ++r) {
            int keyp = mi2 * 16 + quad * 4 + r;            // 0..31
            int dim = ni * 16 + l16;
            int col = (((dim >> 3) ^ (keyp & 7)) << 3) | (dim & 7);
            Tr[keyp * 64 + col] = (_Float16)acc[mi][ni][r];
          }
      }
      #pragma unroll
      for (int j = 0; j < 4; ++j) {
        int wkp = j >> 1, kfl = j & 1;
        int wk = p * 2 + wkp;
        half8_t v = *(const half8_t*)&Tr[(wkp * 16 + l16) * 64 +
                                         (((kfl * 4 + quad) ^ (l16 & 7)) << 3)];
        *(half8_t*)(dstb + wk * 1024 + kfl * 512 + quad * 128 + l16 * 8) = v;
      }
    }
  }
}

// ---------------- fused flash attention v4.1 ----------------
// Barrier-free main loop, fragment-major K/V (base + lane*16B), raw v_exp_f32.
__global__ __launch_bounds__(256, 2) void flash_kernel(const _Float16* __restrict__ QRt,
                                                       const _Float16* __restrict__ QRp,
                                                       const _Float16* __restrict__ KG,
                                                       const _Float16* __restrict__ KGP,
                                                       const _Float16* __restrict__ VG,
                                                       const float* __restrict__ bias_table,
                                                       float* __restrict__ out) {
  __shared__ float biasl[384];
  __shared__ float lred[4][64];
  __shared__ __align__(16) float ored2[2][64][68];

  const int tid = threadIdx.x;
  const int wave = tid >> 6, lane = tid & 63;
  const int quad = lane >> 4, l16 = lane & 15;
  const int lbid = blockIdx.x;
  const int q0 = ((lbid >> 3) & 31) * 64;        // XCD swizzle: same bh
  const int bh = (lbid & 7) + 8 * (lbid >> 8);   // stays on one XCD
  const int b = bh >> 4, h = bh & 15;

  for (int i = tid; i < 384; i += 256) {
    int delta = i - 192;
    int n = -delta;
    int ret = (n < 0) ? 16 : 0;
    int na = (n < 0) ? -n : n;
    int bkt;
    if (na < 8) bkt = na;
    else {
      int s2 = (na >= 12) + (na >= 16) + (na >= 23) + (na >= 32) +
               (na >= 46) + (na >= 64) + (na >= 91) + (na >= 128);
      bkt = 8 + s2; if (bkt > 15) bkt = 15;
    }
    bkt += ret;
    biasl[i] = bias_table[(size_t)(2048 + bkt) * NH + h] * LOG2E;
  }
  const float b_lo = bias_table[(2048 + 15) * NH + h] * LOG2E;
  const float b_hi = bias_table[(2048 + 31) * NH + h] * LOG2E;
  __syncthreads();

  // Q fragments (pre-scaled by 1/sqrt(2*DH)*log2e in gemm epilogue)
  half8_t qf[4][4];
  {
    const _Float16* tq = QRt + (size_t)(b * S_LEN + q0 + l16) * 1024 + h * 64 + quad * 8;
    const _Float16* pq = QRp + (size_t)(q0 + l16) * 1024 + h * 64 + quad * 8;
    #pragma unroll
    for (int qt = 0; qt < 4; ++qt)
      #pragma unroll
      for (int kf = 0; kf < 2; ++kf) {
        qf[kf][qt]     = *(const half8_t*)(tq + (size_t)qt * 16 * 1024 + kf * 32);
        qf[kf + 2][qt] = *(const half8_t*)(pq + (size_t)qt * 16 * 1024 + kf * 32);
      }
  }

  // fragment-major stream pointers (fully coalesced)
  const _Float16* kp_t = KG  + (size_t)bh * 131072 + wave * 1024 + lane * 8;
  const _Float16* kp_p = KGP + (size_t)h  * 131072 + wave * 1024 + lane * 8;
  const _Float16* vp   = VG  + (size_t)bh * 131072 + wave * 1024 + lane * 4;

  f32x4 oa[4][4] = {};
  float lpart[4] = {0.f, 0.f, 0.f, 0.f};

  half8_t ka[4], kb[4];
  half4_t va[4], vb[4];

  auto load_tile = [&](int t, half8_t (&kf_)[4], half4_t (&vf_)[4]) {
    const _Float16* kt = kp_t + t * 4096;
    const _Float16* kp = kp_p + t * 4096;
    kf_[0] = *(const half8_t*)kt;
    kf_[1] = *(const half8_t*)(kt + 512);
    kf_[2] = *(const half8_t*)kp;
    kf_[3] = *(const half8_t*)(kp + 512);
    const _Float16* v = vp + t * 4096;
    #pragma unroll
    for (int d = 0; d < 4; ++d) vf_[d] = *(const half4_t*)(v + d * 256);
  };

  auto compute = [&](int t, half8_t (&kf_)[4], half4_t (&vf_)[4]) {
    f32x4 s[4];
    int dk = t * 64 - q0;
    if (dk < -128 || dk > 128) {
      float c = (dk < 0) ? b_lo : b_hi;
      #pragma unroll
      for (int qt = 0; qt < 4; ++qt) s[qt] = {c, c, c, c};
    } else {
      #pragma unroll
      for (int qt = 0; qt < 4; ++qt) {
        int dbase = dk + wave * 16 + quad * 4 - qt * 16 - l16 + 192;
        #pragma unroll
        for (int r = 0; r < 4; ++r) s[qt][r] = biasl[dbase + r];
      }
    }
    #pragma unroll
    for (int qt = 0; qt < 4; ++qt)
      #pragma unroll
      for (int kf = 0; kf < 4; ++kf)
        s[qt] = mfma_qk(kf_[kf], qf[kf][qt], s[qt]);

    half4_t pf[4];
    #pragma unroll
    for (int qt = 0; qt < 4; ++qt) {
      float p0 = fexp2(s[qt][0]), p1 = fexp2(s[qt][1]);
      float p2 = fexp2(s[qt][2]), p3 = fexp2(s[qt][3]);
      lpart[qt] += (p0 + p1) + (p2 + p3);
      union { half2_t h2[2]; half4_t h4; } u;
      u.h2[0] = __builtin_bit_cast(half2_t, __builtin_amdgcn_cvt_pkrtz(p0, p1));
      u.h2[1] = __builtin_bit_cast(half2_t, __builtin_amdgcn_cvt_pkrtz(p2, p3));
      pf[qt] = u.h4;
    }
    #pragma unroll
    for (int d = 0; d < 4; ++d)
      #pragma unroll
      for (int qt = 0; qt < 4; ++qt)
        oa[d][qt] = mfma_pv(vf_[d], pf[qt], oa[d][qt]);
  };

  load_tile(0, ka, va);
  #pragma unroll 1
  for (int i = 0; i < 16; ++i) {
    int t0 = i * 2;
    load_tile(t0 + 1, kb, vb);
    compute(t0, ka, va);
    if (i != 15) load_tile(t0 + 2, ka, va);
    compute(t0 + 1, kb, vb);
  }

  #pragma unroll
  for (int qt = 0; qt < 4; ++qt) {
    lpart[qt] += __shfl_xor(lpart[qt], 16, 64);
    lpart[qt] += __shfl_xor(lpart[qt], 32, 64);
  }
  if (quad == 0) {
    #pragma unroll
    for (int qt = 0; qt < 4; ++qt) lred[wave][qt * 16 + l16] = lpart[qt];
  }
  if (wave >= 2) {
    #pragma unroll
    for (int d = 0; d < 4; ++d)
      #pragma unroll
      for (int qt = 0; qt < 4; ++qt)
        *(f32x4*)&ored2[wave - 2][qt * 16 + l16][d * 16 + quad * 4] = oa[d][qt];
  }
  __syncthreads();
  if (wave < 2) {
    #pragma unroll
    for (int d = 0; d < 4; ++d)
      #pragma unroll
      for (int qt = 0; qt < 4; ++qt) {
        f32x4 p = *(const f32x4*)&ored2[wave][qt * 16 + l16][d * 16 + quad * 4];
        *(f32x4*)&ored2[wave][qt * 16 + l16][d * 16 + quad * 4] = oa[d][qt] + p;
      }
  }
  __syncthreads();

  #pragma unroll
  for (int c = 0; c < 4; ++c) {
    int chunk = tid + 256 * c;
    int q = chunk >> 4, dc = chunk & 15;
    f32x4 v0 = *(const f32x4*)&ored2[0][q][dc * 4];
    f32x4 v1 = *(const f32x4*)&ored2[1][q][dc * 4];
    f32x4 sum = v0 + v1;
    float l = (lred[0][q] + lred[1][q]) + (lred[2][q] + lred[3][q]);
    float inv = 1.f / l;
    sum[0] *= inv; sum[1] *= inv; sum[2] *= inv; sum[3] *= inv;
    *(f32x4*)(out + (size_t)(b * S_LEN + q0 + q) * 1024 + h * 64 + dc * 4) = sum;
  }
}

extern "C" void kernel_launch(void* const* d_in, const int* in_sizes, int n_in,
                              void* d_out, int out_size, void* d_ws, size_t ws_size,
                              hipStream_t stream) {
  (void)in_sizes; (void)n_in; (void)out_size; (void)ws_size;
  const float* x          = (const float*)d_in[0];
  const float* pos_embed  = (const float*)d_in[1];
  const float* W_pos_kq   = (const float*)d_in[2];
  const float* W_tok_kqv  = (const float*)d_in[3];
  const float* bias_table = (const float*)d_in[4];
  float* out = (float*)d_out;

  _Float16* ws = (_Float16*)d_ws;
  _Float16* pos_f  = ws;                     // 2,097,152
  _Float16* wt_pos = ws + 2097152;           // 2,097,152
  _Float16* x_f    = ws + 4194304;           // 4,194,304
  _Float16* wt_tok = ws + 8388608;           // 3,145,728
  _Float16* KG     = ws + 11534336;          // 4,194,304
  _Float16* KGP    = ws + 15728640;          // 2,097,152
  _Float16* VG     = ws + 17825792;          // 4,194,304
  _Float16* QRt    = ws + 22020096;          // 4,194,304
  _Float16* QRp    = ws + 26214400;          // 2,097,152
  // total 28,311,552 halfs = 56.6 MB (same footprint as the passing R1 layout)

  const float QSCALE = 0.08838834764831845f * LOG2E;  // 1/sqrt(2*64) * log2e

  prep_kernel<<<7424, 256, 0, stream>>>(x, pos_embed, W_pos_kq, W_tok_kqv,
                                        x_f, pos_f, wt_pos, wt_tok);
  gemm_all_kernel<<<1024, 256, 0, stream>>>(pos_f, wt_pos, x_f, wt_tok,
                                            KGP, QRp, KG, QRt, VG, QSCALE);
  flash_kernel<<<1024, 256, 0, stream>>>(QRt, QRp, KG, KGP, VG, bias_table, out);
}